// Round 12
// baseline (61.003 us; speedup 1.0000x reference)
//
#include <hip/hip_runtime.h>

// MakeCutouts: 32 random crops (sz in [224,511]) of a [2,3,512,512] fp32
// image, each adaptive-avg-pooled (PyTorch semantics) to 224x224.
// Output: [32*2, 3, 224, 224] fp32.
//
// R11 = MEASUREMENT ROUND. R4 (best known, 20.9us) repeated REPEAT=5 times
// inside one dispatch (idempotent: every iteration recomputes the same
// output from unchanged inputs; barrier at loop end orders LDS reuse across
// iterations). Purpose: one ~100us dispatch outlasts the harness's ~40us
// poison fills so OUR kernel finally appears in the rocprof top-5 with real
// counters (VALUBusy / SQ_LDS_BANK_CONFLICT / FETCH / WRITE / Occupancy).
// Six structural theories (traffic x3, latency, issue count, barriers) all
// landed 21+-1us; the counters decide what's actually binding.

constexpr int CUT    = 224;
constexpr int BC     = 6;          // B*C = 2*3
constexpr int HH     = 512;
constexpr int WW     = 512;
constexpr int PIX    = CUT * CUT;  // 50176
constexpr int PLANE  = HH * WW;
constexpr int REPEAT = 5;          // measurement multiplier

__global__ __launch_bounds__(256) void cutout_kernel(
    const float* __restrict__ in,     // [6, 512, 512] planes
    const int*   __restrict__ sizes,  // [32]
    const int*   __restrict__ offx,   // [32]
    const int*   __restrict__ offy,   // [32]
    float*       __restrict__ out)    // [32, 6, 224, 224] flat
{
    __shared__ float2 vsum[3][WW];    // [plane-pair][crop col] = 12 KB

    const int i = blockIdx.x;         // output row (uniform)
    const int n = blockIdx.y;         // cutout (uniform)
    const int t = threadIdx.x;

    const int sz = sizes[n];          // uniform -> scalar
    const int oy = offy[n];
    const int ox = offx[n];

    const int sy = (i * sz) / CUT;                        // uniform
    const int dy = ((i + 1) * sz + CUT - 1) / CUT - sy;   // 1..4, uniform

    const float* __restrict__ base = in + (oy + sy) * WW + ox;
    const bool c0 = t < sz;           // sz >= 224; only lanes 224..255 can fail
    const bool c1 = t + 256 < sz;

    for (int iter = 0; iter < REPEAT; ++iter) {
        // Phase 1: vertical sums over dy rows, cols t and t+256 (crop-rel).
        float a0=0.f,a1=0.f,a2=0.f,a3=0.f,a4=0.f,a5=0.f;  // col t
        float b0=0.f,b1=0.f,b2=0.f,b3=0.f,b4=0.f,b5=0.f;  // col t+256
        for (int r = 0; r < dy; ++r) {    // uniform trip count
            const float* __restrict__ rp = base + r * WW;
            if (c0) {
                a0 += rp[0*PLANE + t]; a1 += rp[1*PLANE + t]; a2 += rp[2*PLANE + t];
                a3 += rp[3*PLANE + t]; a4 += rp[4*PLANE + t]; a5 += rp[5*PLANE + t];
            }
            if (c1) {
                const int u = t + 256;
                b0 += rp[0*PLANE + u]; b1 += rp[1*PLANE + u]; b2 += rp[2*PLANE + u];
                b3 += rp[3*PLANE + u]; b4 += rp[4*PLANE + u]; b5 += rp[5*PLANE + u];
            }
        }
        if (c0) {
            vsum[0][t] = make_float2(a0, a1);
            vsum[1][t] = make_float2(a2, a3);
            vsum[2][t] = make_float2(a4, a5);
        }
        if (c1) {
            const int u = t + 256;
            vsum[0][u] = make_float2(b0, b1);
            vsum[1][u] = make_float2(b2, b3);
            vsum[2][u] = make_float2(b4, b5);
        }
        __syncthreads();

        // Phase 2: horizontal pooling from LDS, 4 predicated taps (dx 1..4).
        if (t < CUT) {
            const int sx = (t * sz) / CUT;                        // crop-rel
            const int dx = ((t + 1) * sz + CUT - 1) / CUT - sx;   // 1..4
            const int x1 = sx + (dx > 1 ? 1 : 0);                 // clamped
            const int x2 = x1 + (dx > 2 ? 1 : 0);
            const int x3 = x2 + (dx > 3 ? 1 : 0);
            const float w1 = dx > 1 ? 1.f : 0.f;
            const float w2 = dx > 2 ? 1.f : 0.f;
            const float w3 = dx > 3 ? 1.f : 0.f;
            const float rr = __builtin_amdgcn_rcpf((float)(dy * dx));

            float* o = out + (size_t)n * BC * PIX + i * CUT + t;
            #pragma unroll
            for (int pr = 0; pr < 3; ++pr) {
                const float2 v0 = vsum[pr][sx];
                const float2 v1 = vsum[pr][x1];
                const float2 v2 = vsum[pr][x2];
                const float2 v3 = vsum[pr][x3];
                const float se = v0.x + w1 * v1.x + w2 * v2.x + w3 * v3.x;
                const float so = v0.y + w1 * v1.y + w2 * v2.y + w3 * v3.y;
                __builtin_nontemporal_store(se * rr, o + (2 * pr    ) * PIX);
                __builtin_nontemporal_store(so * rr, o + (2 * pr + 1) * PIX);
            }
        }
        __syncthreads();   // LDS reused next iteration: drain phase-2 reads
    }
}

extern "C" void kernel_launch(void* const* d_in, const int* in_sizes, int n_in,
                              void* d_out, int out_size, void* d_ws, size_t ws_size,
                              hipStream_t stream) {
    const float* in    = (const float*)d_in[0];
    const int*   sizes = (const int*)d_in[1];
    const int*   offx  = (const int*)d_in[2];
    const int*   offy  = (const int*)d_in[3];
    float*       out   = (float*)d_out;

    cutout_kernel<<<dim3(CUT, 32), dim3(256), 0, stream>>>(
        in, sizes, offx, offy, out);
}

// Round 13
// 16.587 us; speedup vs baseline: 3.6778x; 3.6778x over previous
//
#include <hip/hip_runtime.h>

// MakeCutouts: 32 random crops (sz in [224,511]) of a [2,3,512,512] fp32
// image, each adaptive-avg-pooled (PyTorch semantics) to 224x224.
// Output: [32*2, 3, 224, 224] fp32.
//
// R12: R11's REPEAT probe split dur into body B~10us + per-dispatch C~11us
// (C+5B=61, C+B=21). Steady counters: VALUBusy 38%, HBM 53%, occ 70%,
// bank-conflict ~1us/iter -> body is near the 6us write floor; C is the
// COLD-READ FLOOD: 45MB of demand reads miss L2 at dispatch start (input
// 6.3MB > 4MiB/XCD L2; (i,n) grid round-robins adjacent rows across XCDs so
// dy-overlap re-reads never L2-hit). Fix: balanced XCD-affine row chunks.
// 1D grid, xcd = bid&7; XCD x owns rows [28x,28x+28) of EVERY cutout
// (perfect balance - kills R5's per-cutout sz^2 imbalance), consecutive r of
// one cutout dispatch-adjacent on one XCD -> overlap rows hit L2. Body = R4
// (best known) unchanged to isolate the mapping variable.

constexpr int CUT   = 224;
constexpr int BC    = 6;          // B*C = 2*3
constexpr int HH    = 512;
constexpr int WW    = 512;
constexpr int PIX   = CUT * CUT;  // 50176
constexpr int PLANE = HH * WW;
constexpr int CHUNK = CUT / 8;    // 28 rows per XCD per cutout

__global__ __launch_bounds__(256) void cutout_kernel(
    const float* __restrict__ in,     // [6, 512, 512] planes
    const int*   __restrict__ sizes,  // [32]
    const int*   __restrict__ offx,   // [32]
    const int*   __restrict__ offy,   // [32]
    float*       __restrict__ out)    // [32, 6, 224, 224] flat
{
    __shared__ float2 vsum[3][WW];    // [plane-pair][crop col] = 12 KB

    // Balanced XCD-affine decode: bid%8 = XCD (round-robin dispatch),
    // XCD x gets rows 28x..28x+27 of every cutout, r-major within a cutout.
    const int bid = blockIdx.x;
    const int xcd = bid & 7;
    const int idx = bid >> 3;          // 0..895 = n*28 + r
    const int n   = idx / CHUNK;       // cutout
    const int r0  = idx - n * CHUNK;   // 0..27
    const int i   = xcd * CHUNK + r0;  // output row

    const int t = threadIdx.x;

    const int sz = sizes[n];          // uniform -> scalar
    const int oy = offy[n];
    const int ox = offx[n];

    const int sy = (i * sz) / CUT;                        // uniform
    const int dy = ((i + 1) * sz + CUT - 1) / CUT - sy;   // 1..4, uniform

    const float* __restrict__ base = in + (oy + sy) * WW + ox;
    const bool c0 = t < sz;           // sz >= 224; only lanes 224..255 can fail
    const bool c1 = t + 256 < sz;

    // Phase 1: vertical sums over dy rows, cols t and t+256 (crop-relative).
    float a0=0.f,a1=0.f,a2=0.f,a3=0.f,a4=0.f,a5=0.f;  // col t
    float b0=0.f,b1=0.f,b2=0.f,b3=0.f,b4=0.f,b5=0.f;  // col t+256
    for (int r = 0; r < dy; ++r) {    // uniform trip count
        const float* __restrict__ rp = base + r * WW;
        if (c0) {
            a0 += rp[0*PLANE + t]; a1 += rp[1*PLANE + t]; a2 += rp[2*PLANE + t];
            a3 += rp[3*PLANE + t]; a4 += rp[4*PLANE + t]; a5 += rp[5*PLANE + t];
        }
        if (c1) {
            const int u = t + 256;
            b0 += rp[0*PLANE + u]; b1 += rp[1*PLANE + u]; b2 += rp[2*PLANE + u];
            b3 += rp[3*PLANE + u]; b4 += rp[4*PLANE + u]; b5 += rp[5*PLANE + u];
        }
    }
    if (c0) {
        vsum[0][t] = make_float2(a0, a1);
        vsum[1][t] = make_float2(a2, a3);
        vsum[2][t] = make_float2(a4, a5);
    }
    if (c1) {
        const int u = t + 256;
        vsum[0][u] = make_float2(b0, b1);
        vsum[1][u] = make_float2(b2, b3);
        vsum[2][u] = make_float2(b4, b5);
    }
    __syncthreads();

    // Phase 2: horizontal pooling from LDS, 4 predicated taps (dx in 1..4).
    if (t < CUT) {
        const int sx = (t * sz) / CUT;                        // crop-relative
        const int dx = ((t + 1) * sz + CUT - 1) / CUT - sx;   // 1..4
        const int x1 = sx + (dx > 1 ? 1 : 0);                 // clamped taps
        const int x2 = x1 + (dx > 2 ? 1 : 0);
        const int x3 = x2 + (dx > 3 ? 1 : 0);
        const float w1 = dx > 1 ? 1.f : 0.f;
        const float w2 = dx > 2 ? 1.f : 0.f;
        const float w3 = dx > 3 ? 1.f : 0.f;
        const float rr = __builtin_amdgcn_rcpf((float)(dy * dx));

        float* o = out + (size_t)n * BC * PIX + i * CUT + t;
        #pragma unroll
        for (int pr = 0; pr < 3; ++pr) {
            const float2 v0 = vsum[pr][sx];
            const float2 v1 = vsum[pr][x1];
            const float2 v2 = vsum[pr][x2];
            const float2 v3 = vsum[pr][x3];
            const float se = v0.x + w1 * v1.x + w2 * v2.x + w3 * v3.x;
            const float so = v0.y + w1 * v1.y + w2 * v2.y + w3 * v3.y;
            __builtin_nontemporal_store(se * rr, o + (2 * pr    ) * PIX);
            __builtin_nontemporal_store(so * rr, o + (2 * pr + 1) * PIX);
        }
    }
}

extern "C" void kernel_launch(void* const* d_in, const int* in_sizes, int n_in,
                              void* d_out, int out_size, void* d_ws, size_t ws_size,
                              hipStream_t stream) {
    const float* in    = (const float*)d_in[0];
    const int*   sizes = (const int*)d_in[1];
    const int*   offx  = (const int*)d_in[2];
    const int*   offy  = (const int*)d_in[3];
    float*       out   = (float*)d_out;

    cutout_kernel<<<dim3(CUT * 32), dim3(256), 0, stream>>>(
        in, sizes, offx, offy, out);
}